// Round 1
// baseline (565.200 us; speedup 1.0000x reference)
//
#include <hip/hip_runtime.h>
#include <math.h>

#define N_NODES 100000
#define C_CH    64
#define E_EDGES 1200000
#define KD      32
#define HID     256
#define NPG     32
#define NGROUPS (N_NODES / NPG)     // 3125 exact
#define NCHUNK  (E_EDGES / 64)      // 18750 exact
#define NB_SCAN ((N_NODES + 1023) / 1024)   // 98

typedef unsigned short ushort_t;
typedef short bf16x8 __attribute__((ext_vector_type(8)));
typedef short s2v    __attribute__((ext_vector_type(2)));
typedef float f32x4  __attribute__((ext_vector_type(4)));

__device__ __forceinline__ short f2bf(float f) {
    unsigned u = __builtin_bit_cast(unsigned, f);
    u = (u + 0x7fffu + ((u >> 16) & 1u)) >> 16;   // RNE
    return (short)u;
}
__device__ __forceinline__ float bf2f(ushort_t u) {
    return __builtin_bit_cast(float, (unsigned)u << 16);
}
__device__ __forceinline__ float bf2f_lo(unsigned p) {
    return __builtin_bit_cast(float, p << 16);
}
__device__ __forceinline__ float bf2f_hi(unsigned p) {
    return __builtin_bit_cast(float, p & 0xffff0000u);
}

// packed bf16x2 atomic add (HW global_atomic_pk_add_bf16 on gfx950)
__device__ __forceinline__ void pk_atomic_bf16(void* p, float m0, float m1) {
    s2v v; v[0] = f2bf(m0); v[1] = f2bf(m1);
#if __has_builtin(__builtin_amdgcn_global_atomic_fadd_v2bf16)
    typedef __attribute__((address_space(1))) s2v* gpt;
    __builtin_amdgcn_global_atomic_fadd_v2bf16((gpt)(unsigned long long)p, v);
#else
    unsigned* up = (unsigned*)p;
    unsigned old = __hip_atomic_load(up, __ATOMIC_RELAXED, __HIP_MEMORY_SCOPE_AGENT);
    unsigned assumed;
    do {
        assumed = old;
        float a0 = bf2f_lo(assumed) + m0;
        float a1 = bf2f_hi(assumed) + m1;
        unsigned nv = (unsigned)(ushort_t)f2bf(a0)
                    | ((unsigned)(ushort_t)f2bf(a1) << 16);
        old = atomicCAS(up, assumed, nv);
    } while (old != assumed);
#endif
}

// ---------------------------------------------------------------------------
// Counting-sort of edges by dst:
//   hist -> scan1 (per-1024-block excl scan) -> scan2 (scan of 98 partials)
//   -> scan3 (add partials) -> scatter (claim position, write {eid,src,dst}).
// Rationale: edge_kernel was atomic-path-bound (WRITE_SIZE == E*C*2B, 263G
// atomic-ops/s, all other pipes <35%). Sorting makes equal-dst edges
// contiguous so the conv kernel can accumulate runs in registers and flush
// with ~5x fewer pk-bf16 atomics (avg in-degree 12, window 8).
// ---------------------------------------------------------------------------
__global__ __launch_bounds__(256) void hist_kernel(
    const int* __restrict__ ei, int* __restrict__ cnt)
{
    for (int e = blockIdx.x * 256 + threadIdx.x; e < E_EDGES;
         e += gridDim.x * 256)
        atomicAdd(&cnt[ei[E_EDGES + e]], 1);
}

__global__ __launch_bounds__(256) void scan1_kernel(
    const int* __restrict__ cnt, int* __restrict__ cursor,
    int* __restrict__ part)
{
    __shared__ int s[256];
    const int b  = blockIdx.x;
    const int t  = threadIdx.x;
    const int i0 = b * 1024 + t * 4;
    int v0 = 0, v1 = 0, v2 = 0, v3 = 0;
    if (i0 + 3 < N_NODES) {
        const int4 c4 = *(const int4*)(cnt + i0);
        v0 = c4.x; v1 = c4.y; v2 = c4.z; v3 = c4.w;
    } else {
        if (i0 + 0 < N_NODES) v0 = cnt[i0 + 0];
        if (i0 + 1 < N_NODES) v1 = cnt[i0 + 1];
        if (i0 + 2 < N_NODES) v2 = cnt[i0 + 2];
        if (i0 + 3 < N_NODES) v3 = cnt[i0 + 3];
    }
    const int sum = v0 + v1 + v2 + v3;
    s[t] = sum;
    __syncthreads();
    #pragma unroll
    for (int o = 1; o < 256; o <<= 1) {
        const int add = (t >= o) ? s[t - o] : 0;
        __syncthreads();
        s[t] += add;
        __syncthreads();
    }
    const int excl = s[t] - sum;
    if (t == 255) part[b] = s[255];
    int run = excl;
    if (i0 + 0 < N_NODES) cursor[i0 + 0] = run;
    run += v0;
    if (i0 + 1 < N_NODES) cursor[i0 + 1] = run;
    run += v1;
    if (i0 + 2 < N_NODES) cursor[i0 + 2] = run;
    run += v2;
    if (i0 + 3 < N_NODES) cursor[i0 + 3] = run;
}

__global__ __launch_bounds__(128) void scan2_kernel(int* __restrict__ part)
{
    __shared__ int s[128];
    const int t = threadIdx.x;
    const int v = (t < NB_SCAN) ? part[t] : 0;
    s[t] = v;
    __syncthreads();
    #pragma unroll
    for (int o = 1; o < 128; o <<= 1) {
        const int add = (t >= o) ? s[t - o] : 0;
        __syncthreads();
        s[t] += add;
        __syncthreads();
    }
    if (t < NB_SCAN) part[t] = s[t] - v;   // exclusive
}

__global__ __launch_bounds__(256) void scan3_kernel(
    int* __restrict__ cursor, const int* __restrict__ part)
{
    const int b   = blockIdx.x;
    const int add = part[b];
    const int i0  = b * 1024 + threadIdx.x * 4;
    #pragma unroll
    for (int k = 0; k < 4; ++k)
        if (i0 + k < N_NODES) cursor[i0 + k] += add;
}

__global__ __launch_bounds__(256) void scatter_kernel(
    const int* __restrict__ ei, int* __restrict__ cursor,
    int4* __restrict__ sorted)
{
    for (int e = blockIdx.x * 256 + threadIdx.x; e < E_EDGES;
         e += gridDim.x * 256) {
        const int src = ei[e];
        const int dst = ei[E_EDGES + e];
        const int pos = atomicAdd(&cursor[dst], 1);
        sorted[pos] = make_int4(e, src, dst, 0);
    }
}

// ---------------------------------------------------------------------------
// K1': conv over dst-sorted edges. MFMA structure identical to edge_kernel
// (A = kb rows of the tile's 16 edges, B = preloaded kW), but the scatter
// phase walks 8 sorted edges per half-wave, accumulating equal-dst runs in
// fp32 registers and flushing one pk-bf16 atomic per run fragment.
// ---------------------------------------------------------------------------
__global__ __launch_bounds__(256) void conv_kernel(
    const float* __restrict__ x, const float* __restrict__ kb,
    const int4* __restrict__ sorted, const float* __restrict__ kW,
    ushort_t* __restrict__ x1b)
{
    __shared__ int cbuf[4][16][34];   // 8.7 KB: [wave][edge-row][dword]

    const int t    = threadIdx.x;
    const int lane = t & 63;
    const int w    = __builtin_amdgcn_readfirstlane(t >> 6);
    const int nlo  = lane & 15;
    const int quad = lane >> 4;
    const int cp   = lane & 31;       // channel-pair index
    const int hf   = lane >> 5;       // half-wave: edges [0,8) vs [8,16)

    // B fragments: B[k][n] = kW[16t+n][k], lane k = quad*8+j
    bf16x8 bW[4];
    #pragma unroll
    for (int tt = 0; tt < 4; ++tt) {
        const float* p = kW + (size_t)(16 * tt + nlo) * KD + quad * 8;
        #pragma unroll
        for (int q = 0; q < 8; ++q) bW[tt][q] = f2bf(p[q]);
    }

    short* srow = (short*)&cbuf[w][0][0];   // row stride 68 shorts

    for (int c = blockIdx.x; c < NCHUNK; c += gridDim.x) {
        const int p0 = c * 64 + w * 16;
        const int4 s4 = sorted[p0 + nlo];   // {eid, src, dst, 0} for edge nlo

        // ---- MFMA coef for the 16 sorted edges of this wave ----
        const float* ap = kb + (size_t)s4.x * KD + quad * 8;
        bf16x8 af;
        #pragma unroll
        for (int q = 0; q < 8; ++q) af[q] = f2bf(ap[q]);
        #pragma unroll
        for (int tt = 0; tt < 4; ++tt) {
            f32x4 d = {0.f, 0.f, 0.f, 0.f};
            d = __builtin_amdgcn_mfma_f32_16x16x32_bf16(af, bW[tt], d, 0, 0, 0);
            #pragma unroll
            for (int r = 0; r < 4; ++r)
                srow[(quad * 4 + r) * 68 + 16 * tt + nlo] = f2bf(d[r]);
        }
        __syncthreads();

        // ---- run-accumulating scatter: half-wave walks 8 sorted edges ----
        float a0 = 0.f, a1 = 0.f;
        #pragma unroll
        for (int j = 0; j < 8; ++j) {
            const int srcj = __shfl(s4.y, hf * 8 + j, 64);
            const int dstj = __shfl(s4.z, hf * 8 + j, 64);
            const int dnxt = (j < 7) ? __shfl(s4.z, hf * 8 + j + 1, 64) : -1;
            const unsigned cf = (unsigned)cbuf[w][j + hf * 8][cp];
            const float2 x2 = *(const float2*)(x + (size_t)srcj * C_CH + 2 * cp);
            a0 += x2.x * bf2f_lo(cf);
            a1 += x2.y * bf2f_hi(cf);
            if (dnxt != dstj) {   // uniform within half-wave
                pk_atomic_bf16(x1b + (size_t)dstj * C_CH + 2 * cp, a0, a1);
                a0 = 0.f; a1 = 0.f;
            }
        }
        __syncthreads();
    }
}

// ---------------------------------------------------------------------------
// K1 fallback (previous kernel): per-edge atomics, used if ws_size too small.
// ---------------------------------------------------------------------------
__global__ __launch_bounds__(256) void edge_kernel(
    const float* __restrict__ x, const float* __restrict__ kb,
    const int* __restrict__ ei, const float* __restrict__ kW,
    ushort_t* __restrict__ x1b)
{
    __shared__ int cbuf[4][16][34];

    const int t    = threadIdx.x;
    const int lane = t & 63;
    const int w    = __builtin_amdgcn_readfirstlane(t >> 6);
    const int nlo  = lane & 15;
    const int quad = lane >> 4;
    const int cp   = lane & 31;
    const int hf   = lane >> 5;

    bf16x8 bW[4];
    #pragma unroll
    for (int tt = 0; tt < 4; ++tt) {
        const float* p = kW + (size_t)(16 * tt + nlo) * KD + quad * 8;
        #pragma unroll
        for (int q = 0; q < 8; ++q) bW[tt][q] = f2bf(p[q]);
    }

    short* srow = (short*)&cbuf[w][0][0];

    for (int c = blockIdx.x; c < NCHUNK; c += gridDim.x) {
        const int e0 = c * 64 + w * 16;

        const float* ap = kb + (size_t)(e0 + nlo) * KD + quad * 8;
        bf16x8 af;
        #pragma unroll
        for (int q = 0; q < 8; ++q) af[q] = f2bf(ap[q]);
        #pragma unroll
        for (int tt = 0; tt < 4; ++tt) {
            f32x4 d = {0.f, 0.f, 0.f, 0.f};
            d = __builtin_amdgcn_mfma_f32_16x16x32_bf16(af, bW[tt], d, 0, 0, 0);
            #pragma unroll
            for (int r = 0; r < 4; ++r)
                srow[(quad * 4 + r) * 68 + 16 * tt + nlo] = f2bf(d[r]);
        }
        __syncthreads();

        #pragma unroll
        for (int j = 0; j < 8; ++j) {
            const int sA = ei[e0 + j],           sB = ei[e0 + j + 8];
            const int dA = ei[E_EDGES + e0 + j], dB = ei[E_EDGES + e0 + j + 8];
            const int src = hf ? sB : sA;
            const int dst = hf ? dB : dA;
            const unsigned cf = (unsigned)cbuf[w][j + hf * 8][cp];
            const float2 x2 = *(const float2*)(x + (size_t)src * C_CH + 2 * cp);
            pk_atomic_bf16(x1b + (size_t)dst * C_CH + 2 * cp,
                           x2.x * bf2f_lo(cf), x2.y * bf2f_hi(cf));
        }
        __syncthreads();
    }
}

// ---------------------------------------------------------------------------
// K2: conv_bias + LN (fp32) -> bf16 MFMA GEMM1 -> exact GELU -> bf16 MFMA
// GEMM2 -> layerscale + residual. x1 is bf16. (unchanged this round)
// ---------------------------------------------------------------------------
__global__ __launch_bounds__(256, 2) void node_kernel(
    const float* __restrict__ x,  const ushort_t* __restrict__ x1b,
    const float* __restrict__ conv_bias, const float* __restrict__ gamma,
    const float* __restrict__ beta, const float* __restrict__ W1,
    const float* __restrict__ b1, const float* __restrict__ W2,
    const float* __restrict__ b2, const float* __restrict__ ls,
    float* __restrict__ out)
{
    __shared__ short lnb[NPG][C_CH + 8];
    __shared__ short gb[NPG][HID + 8];

    const int t    = threadIdx.x;
    const int lane = t & 63;
    const int w    = t >> 6;
    const int nlo  = lane & 15;
    const int quad = lane >> 4;

    bf16x8 b1f[4][2];
    float  b1v[4];
    #pragma unroll
    for (int t1 = 0; t1 < 4; ++t1) {
        const int j = (4 * w + t1) * 16 + nlo;
        b1v[t1] = b1[j];
        #pragma unroll
        for (int s = 0; s < 2; ++s) {
            const float* p = W1 + (size_t)j * C_CH + s * 32 + quad * 8;
            #pragma unroll
            for (int q = 0; q < 8; ++q) b1f[t1][s][q] = f2bf(p[q]);
        }
    }
    bf16x8 b2f[8];
    #pragma unroll
    for (int s2 = 0; s2 < 8; ++s2) {
        const float* p = W2 + (size_t)(w * 16 + nlo) * HID + s2 * 32 + quad * 8;
        #pragma unroll
        for (int q = 0; q < 8; ++q) b2f[s2][q] = f2bf(p[q]);
    }
    const float biasc  = conv_bias[lane];
    const float gammac = gamma[lane];
    const float betac  = beta[lane];
    const float b2v    = b2[w * 16 + nlo];
    const float lsv    = ls[w * 16 + nlo];

    for (int g = blockIdx.x; g < NGROUPS; g += gridDim.x) {
        const int base = g * NPG;

        #pragma unroll
        for (int q = 0; q < 8; ++q) {
            const int loc = w * 8 + q;
            float v = bf2f(x1b[(size_t)(base + loc) * C_CH + lane]) + biasc;
            float s = v, ss = v * v;
            #pragma unroll
            for (int o = 32; o > 0; o >>= 1) {
                s  += __shfl_xor(s,  o, 64);
                ss += __shfl_xor(ss, o, 64);
            }
            float mu   = s * (1.f / 64.f);
            float rstd = rsqrtf(ss * (1.f / 64.f) - mu * mu + 1e-5f);
            lnb[loc][lane] = f2bf((v - mu) * rstd * gammac + betac);
        }
        __syncthreads();

        #pragma unroll
        for (int mt = 0; mt < 2; ++mt) {
            bf16x8 a1[2];
            #pragma unroll
            for (int s = 0; s < 2; ++s)
                a1[s] = *(const bf16x8*)&lnb[mt * 16 + nlo][s * 32 + quad * 8];
            #pragma unroll
            for (int t1 = 0; t1 < 4; ++t1) {
                f32x4 c = {0.f, 0.f, 0.f, 0.f};
                c = __builtin_amdgcn_mfma_f32_16x16x32_bf16(a1[0], b1f[t1][0], c, 0, 0, 0);
                c = __builtin_amdgcn_mfma_f32_16x16x32_bf16(a1[1], b1f[t1][1], c, 0, 0, 0);
                #pragma unroll
                for (int r = 0; r < 4; ++r) {
                    float h = c[r] + b1v[t1];
                    h = 0.5f * h * (1.f + erff(h * 0.70710678f));
                    gb[mt * 16 + quad * 4 + r][(4 * w + t1) * 16 + nlo] = f2bf(h);
                }
            }
        }
        __syncthreads();

        #pragma unroll
        for (int mt = 0; mt < 2; ++mt) {
            f32x4 c2 = {0.f, 0.f, 0.f, 0.f};
            #pragma unroll
            for (int s2 = 0; s2 < 8; ++s2) {
                bf16x8 a2 = *(const bf16x8*)&gb[mt * 16 + nlo][s2 * 32 + quad * 8];
                c2 = __builtin_amdgcn_mfma_f32_16x16x32_bf16(a2, b2f[s2], c2, 0, 0, 0);
            }
            #pragma unroll
            for (int r = 0; r < 4; ++r) {
                const int node = base + mt * 16 + quad * 4 + r;
                const int cch  = w * 16 + nlo;
                float h2 = c2[r] + b2v;
                out[(size_t)node * C_CH + cch] =
                    lsv * h2 + x[(size_t)node * C_CH + cch];
            }
        }
        __syncthreads();
    }
}

extern "C" void kernel_launch(void* const* d_in, const int* in_sizes, int n_in,
                              void* d_out, int out_size, void* d_ws, size_t ws_size,
                              hipStream_t stream) {
    const float* x   = (const float*)d_in[0];
    const float* kb  = (const float*)d_in[1];
    // d_in[2] = fiber_kernel_basis (unused)
    const int*   ei  = (const int*)d_in[3];
    const float* kW  = (const float*)d_in[4];
    const float* cb  = (const float*)d_in[5];
    const float* gm  = (const float*)d_in[6];
    const float* bt  = (const float*)d_in[7];
    const float* W1  = (const float*)d_in[8];
    const float* b1  = (const float*)d_in[9];
    const float* W2  = (const float*)d_in[10];
    const float* b2  = (const float*)d_in[11];
    const float* ls  = (const float*)d_in[12];
    float* out = (float*)d_out;

    // workspace layout (all 16B-aligned given 16B-aligned d_ws)
    char* wsb = (char*)d_ws;
    const size_t off_x1b    = 0;                              // 12,800,000 B
    const size_t off_cnt    = 12800000;                       //    400,000 B
    const size_t off_cur    = off_cnt  + 400000;              //    400,000 B
    const size_t off_part   = off_cur  + 400000;              //        512 B
    const size_t off_sorted = off_part + 512;                 // 19,200,000 B
    const size_t need       = off_sorted + (size_t)E_EDGES * 16;

    ushort_t* x1b = (ushort_t*)(wsb + off_x1b);
    hipMemsetAsync(x1b, 0, (size_t)N_NODES * C_CH * sizeof(ushort_t), stream);

    if (ws_size >= need) {
        int*  cnt    = (int*)(wsb + off_cnt);
        int*  cur    = (int*)(wsb + off_cur);
        int*  part   = (int*)(wsb + off_part);
        int4* sorted = (int4*)(wsb + off_sorted);

        hipMemsetAsync(cnt, 0, (size_t)N_NODES * sizeof(int), stream);
        hist_kernel<<<2048, 256, 0, stream>>>(ei, cnt);
        scan1_kernel<<<NB_SCAN, 256, 0, stream>>>(cnt, cur, part);
        scan2_kernel<<<1, 128, 0, stream>>>(part);
        scan3_kernel<<<NB_SCAN, 256, 0, stream>>>(cur, part);
        scatter_kernel<<<2048, 256, 0, stream>>>(ei, cur, sorted);
        conv_kernel<<<4096, 256, 0, stream>>>(x, kb, sorted, kW, x1b);
    } else {
        edge_kernel<<<4096, 256, 0, stream>>>(x, kb, ei, kW, x1b);
    }

    node_kernel<<<2048, 256, 0, stream>>>(x, x1b, cb, gm, bt, W1, b1, W2, b2, ls, out);
}

// Round 4
// 410.049 us; speedup vs baseline: 1.3784x; 1.3784x over previous
//
#include <hip/hip_runtime.h>
#include <math.h>

#define N_NODES 100000
#define C_CH    64
#define E_EDGES 1200000
#define KD      32
#define HID     256
#define NPG     32
#define NGROUPS (N_NODES / NPG)     // 3125 exact
#define NCHUNK  (E_EDGES / 64)      // 18750 exact

typedef unsigned short ushort_t;
typedef short bf16x8 __attribute__((ext_vector_type(8)));
typedef short s2v    __attribute__((ext_vector_type(2)));
typedef float f32x4  __attribute__((ext_vector_type(4)));

__device__ __forceinline__ short f2bf(float f) {
    unsigned u = __builtin_bit_cast(unsigned, f);
    u = (u + 0x7fffu + ((u >> 16) & 1u)) >> 16;   // RNE
    return (short)u;
}
__device__ __forceinline__ float bf2f(ushort_t u) {
    return __builtin_bit_cast(float, (unsigned)u << 16);
}
__device__ __forceinline__ float bf2f_lo(unsigned p) {
    return __builtin_bit_cast(float, p << 16);
}
__device__ __forceinline__ float bf2f_hi(unsigned p) {
    return __builtin_bit_cast(float, p & 0xffff0000u);
}

// packed bf16x2 atomic add (HW global_atomic_pk_add_bf16 on gfx950)
__device__ __forceinline__ void pk_atomic_bf16(void* p, float m0, float m1) {
    s2v v; v[0] = f2bf(m0); v[1] = f2bf(m1);
#if __has_builtin(__builtin_amdgcn_global_atomic_fadd_v2bf16)
    typedef __attribute__((address_space(1))) s2v* gpt;
    __builtin_amdgcn_global_atomic_fadd_v2bf16((gpt)(unsigned long long)p, v);
#else
    unsigned* up = (unsigned*)p;
    unsigned old = __hip_atomic_load(up, __ATOMIC_RELAXED, __HIP_MEMORY_SCOPE_AGENT);
    unsigned assumed;
    do {
        assumed = old;
        float a0 = bf2f_lo(assumed) + m0;
        float a1 = bf2f_hi(assumed) + m1;
        unsigned nv = (unsigned)(ushort_t)f2bf(a0)
                    | ((unsigned)(ushort_t)f2bf(a1) << 16);
        old = atomicCAS(up, assumed, nv);
    } while (old != assumed);
#endif
}

// ---------------------------------------------------------------------------
// xcast: x fp32 -> bf16 (streaming, ~8 us). Halves the edge kernel's random
// x-gather line demand (two 128B lines per edge -> one), which R0/R1
// invariance fingered as the limiter (both pinned at 307MB/146us = 2.1 TB/s
// on the gather path). Numerically safe: the message path is scaled by
// layer_scale=1e-6 in out; the fp32 residual x is read by node_kernel.
// ---------------------------------------------------------------------------
__global__ __launch_bounds__(256) void xcast_kernel(
    const float* __restrict__ x, ushort_t* __restrict__ xb)
{
    const int stride = gridDim.x * 256;
    for (int k = blockIdx.x * 256 + threadIdx.x; k < N_NODES * C_CH / 4;
         k += stride) {
        const float4 v = *(const float4*)(x + 4 * (size_t)k);
        s2v a, b;
        a[0] = f2bf(v.x); a[1] = f2bf(v.y);
        b[0] = f2bf(v.z); b[1] = f2bf(v.w);
        uint2 o;
        o.x = __builtin_bit_cast(unsigned, a);
        o.y = __builtin_bit_cast(unsigned, b);
        *(uint2*)(xb + 4 * (size_t)k) = o;
    }
}

// ---------------------------------------------------------------------------
// K1 v4: R0's proven barrier structure (R3's barrier-free variant NaN'd —
// the __syncthreads pair is load-bearing beyond inter-wave ordering; do not
// remove without a debugging hold). Single change vs R0: x gathered as bf16
// (4 B/lane, one 128B line per edge-row instead of two).
// Per 16-edge tile per wave:
//   coef[m][ch] = kb[e0+m] . kW[ch]  via 4x mfma_16x16x32_bf16
//   coef -> per-wave LDS (stride 34 dwords, 2-way bank aliasing = free)
//   scatter: 8 iters; lanes 0-31 edge j, lanes 32-63 edge j+8; each lane:
//   ds_read dword coef pair + bf16x2 x load + pk bf16 atomic.
// ---------------------------------------------------------------------------
__global__ __launch_bounds__(256) void edge_kernel(
    const ushort_t* __restrict__ xb, const float* __restrict__ kb,
    const int* __restrict__ ei, const float* __restrict__ kW,
    ushort_t* __restrict__ x1b)
{
    __shared__ int cbuf[4][16][34];   // 8.7 KB: [wave][edge-row][dword]

    const int t    = threadIdx.x;
    const int lane = t & 63;
    const int w    = __builtin_amdgcn_readfirstlane(t >> 6);
    const int nlo  = lane & 15;
    const int quad = lane >> 4;
    const int cp   = lane & 31;       // channel-pair index
    const int hf   = lane >> 5;       // half-wave: edge j vs j+8

    // B fragments: B[k][n] = kW[16t+n][k], lane k = quad*8+j
    bf16x8 bW[4];
    #pragma unroll
    for (int tt = 0; tt < 4; ++tt) {
        const float* p = kW + (size_t)(16 * tt + nlo) * KD + quad * 8;
        #pragma unroll
        for (int q = 0; q < 8; ++q) bW[tt][q] = f2bf(p[q]);
    }

    short* srow = (short*)&cbuf[w][0][0];   // row stride 68 shorts

    for (int c = blockIdx.x; c < NCHUNK; c += gridDim.x) {
        const int e0 = c * 64 + w * 16;

        // ---- MFMA coef for edges e0..e0+15 ----
        const float* ap = kb + (size_t)(e0 + nlo) * KD + quad * 8;
        bf16x8 af;
        #pragma unroll
        for (int q = 0; q < 8; ++q) af[q] = f2bf(ap[q]);
        #pragma unroll
        for (int tt = 0; tt < 4; ++tt) {
            f32x4 d = {0.f, 0.f, 0.f, 0.f};
            d = __builtin_amdgcn_mfma_f32_16x16x32_bf16(af, bW[tt], d, 0, 0, 0);
            #pragma unroll
            for (int r = 0; r < 4; ++r)
                srow[(quad * 4 + r) * 68 + 16 * tt + nlo] = f2bf(d[r]);
        }
        __syncthreads();

        // ---- scatter: 2 edges per instruction slot, full 64-lane use ----
        #pragma unroll
        for (int j = 0; j < 8; ++j) {
            const int sA = ei[e0 + j],           sB = ei[e0 + j + 8];
            const int dA = ei[E_EDGES + e0 + j], dB = ei[E_EDGES + e0 + j + 8];
            const int src = hf ? sB : sA;
            const int dst = hf ? dB : dA;
            const unsigned cf = (unsigned)cbuf[w][j + hf * 8][cp];
            const unsigned xv = *(const unsigned*)(xb + (size_t)src * C_CH + 2 * cp);
            pk_atomic_bf16(x1b + (size_t)dst * C_CH + 2 * cp,
                           bf2f_lo(xv) * bf2f_lo(cf),
                           bf2f_hi(xv) * bf2f_hi(cf));
        }
        __syncthreads();
    }
}

// ---------------------------------------------------------------------------
// K2: conv_bias + LN (fp32) -> bf16 MFMA GEMM1 -> exact GELU -> bf16 MFMA
// GEMM2 -> layerscale + residual. x1 is bf16. (unchanged)
// ---------------------------------------------------------------------------
__global__ __launch_bounds__(256, 2) void node_kernel(
    const float* __restrict__ x,  const ushort_t* __restrict__ x1b,
    const float* __restrict__ conv_bias, const float* __restrict__ gamma,
    const float* __restrict__ beta, const float* __restrict__ W1,
    const float* __restrict__ b1, const float* __restrict__ W2,
    const float* __restrict__ b2, const float* __restrict__ ls,
    float* __restrict__ out)
{
    __shared__ short lnb[NPG][C_CH + 8];
    __shared__ short gb[NPG][HID + 8];

    const int t    = threadIdx.x;
    const int lane = t & 63;
    const int w    = t >> 6;
    const int nlo  = lane & 15;
    const int quad = lane >> 4;

    bf16x8 b1f[4][2];
    float  b1v[4];
    #pragma unroll
    for (int t1 = 0; t1 < 4; ++t1) {
        const int j = (4 * w + t1) * 16 + nlo;
        b1v[t1] = b1[j];
        #pragma unroll
        for (int s = 0; s < 2; ++s) {
            const float* p = W1 + (size_t)j * C_CH + s * 32 + quad * 8;
            #pragma unroll
            for (int q = 0; q < 8; ++q) b1f[t1][s][q] = f2bf(p[q]);
        }
    }
    bf16x8 b2f[8];
    #pragma unroll
    for (int s2 = 0; s2 < 8; ++s2) {
        const float* p = W2 + (size_t)(w * 16 + nlo) * HID + s2 * 32 + quad * 8;
        #pragma unroll
        for (int q = 0; q < 8; ++q) b2f[s2][q] = f2bf(p[q]);
    }
    const float biasc  = conv_bias[lane];
    const float gammac = gamma[lane];
    const float betac  = beta[lane];
    const float b2v    = b2[w * 16 + nlo];
    const float lsv    = ls[w * 16 + nlo];

    for (int g = blockIdx.x; g < NGROUPS; g += gridDim.x) {
        const int base = g * NPG;

        #pragma unroll
        for (int q = 0; q < 8; ++q) {
            const int loc = w * 8 + q;
            float v = bf2f(x1b[(size_t)(base + loc) * C_CH + lane]) + biasc;
            float s = v, ss = v * v;
            #pragma unroll
            for (int o = 32; o > 0; o >>= 1) {
                s  += __shfl_xor(s,  o, 64);
                ss += __shfl_xor(ss, o, 64);
            }
            float mu   = s * (1.f / 64.f);
            float rstd = rsqrtf(ss * (1.f / 64.f) - mu * mu + 1e-5f);
            lnb[loc][lane] = f2bf((v - mu) * rstd * gammac + betac);
        }
        __syncthreads();

        #pragma unroll
        for (int mt = 0; mt < 2; ++mt) {
            bf16x8 a1[2];
            #pragma unroll
            for (int s = 0; s < 2; ++s)
                a1[s] = *(const bf16x8*)&lnb[mt * 16 + nlo][s * 32 + quad * 8];
            #pragma unroll
            for (int t1 = 0; t1 < 4; ++t1) {
                f32x4 c = {0.f, 0.f, 0.f, 0.f};
                c = __builtin_amdgcn_mfma_f32_16x16x32_bf16(a1[0], b1f[t1][0], c, 0, 0, 0);
                c = __builtin_amdgcn_mfma_f32_16x16x32_bf16(a1[1], b1f[t1][1], c, 0, 0, 0);
                #pragma unroll
                for (int r = 0; r < 4; ++r) {
                    float h = c[r] + b1v[t1];
                    h = 0.5f * h * (1.f + erff(h * 0.70710678f));
                    gb[mt * 16 + quad * 4 + r][(4 * w + t1) * 16 + nlo] = f2bf(h);
                }
            }
        }
        __syncthreads();

        #pragma unroll
        for (int mt = 0; mt < 2; ++mt) {
            f32x4 c2 = {0.f, 0.f, 0.f, 0.f};
            #pragma unroll
            for (int s2 = 0; s2 < 8; ++s2) {
                bf16x8 a2 = *(const bf16x8*)&gb[mt * 16 + nlo][s2 * 32 + quad * 8];
                c2 = __builtin_amdgcn_mfma_f32_16x16x32_bf16(a2, b2f[s2], c2, 0, 0, 0);
            }
            #pragma unroll
            for (int r = 0; r < 4; ++r) {
                const int node = base + mt * 16 + quad * 4 + r;
                const int cch  = w * 16 + nlo;
                float h2 = c2[r] + b2v;
                out[(size_t)node * C_CH + cch] =
                    lsv * h2 + x[(size_t)node * C_CH + cch];
            }
        }
        __syncthreads();
    }
}

extern "C" void kernel_launch(void* const* d_in, const int* in_sizes, int n_in,
                              void* d_out, int out_size, void* d_ws, size_t ws_size,
                              hipStream_t stream) {
    const float* x   = (const float*)d_in[0];
    const float* kb  = (const float*)d_in[1];
    // d_in[2] = fiber_kernel_basis (unused)
    const int*   ei  = (const int*)d_in[3];
    const float* kW  = (const float*)d_in[4];
    const float* cb  = (const float*)d_in[5];
    const float* gm  = (const float*)d_in[6];
    const float* bt  = (const float*)d_in[7];
    const float* W1  = (const float*)d_in[8];
    const float* b1  = (const float*)d_in[9];
    const float* W2  = (const float*)d_in[10];
    const float* b2  = (const float*)d_in[11];
    const float* ls  = (const float*)d_in[12];
    float* out = (float*)d_out;

    // workspace: x1b bf16 accumulator (12.8 MB) + xb bf16 copy of x (12.8 MB)
    ushort_t* x1b = (ushort_t*)d_ws;
    ushort_t* xb  = (ushort_t*)d_ws + (size_t)N_NODES * C_CH;

    hipMemsetAsync(x1b, 0, (size_t)N_NODES * C_CH * sizeof(ushort_t), stream);
    xcast_kernel<<<1024, 256, 0, stream>>>(x, xb);
    edge_kernel<<<4096, 256, 0, stream>>>(xb, kb, ei, kW, x1b);
    node_kernel<<<2048, 256, 0, stream>>>(x, x1b, cb, gm, bt, W1, b1, W2, b2, ls, out);
}

// Round 6
// 408.398 us; speedup vs baseline: 1.3839x; 1.0040x over previous
//
#include <hip/hip_runtime.h>
#include <math.h>

#define N_NODES 100000
#define C_CH    64
#define E_EDGES 1200000
#define KD      32
#define HID     256
#define NPG     32
#define NGROUPS (N_NODES / NPG)     // 3125 exact
#define NCHUNK  (E_EDGES / 64)      // 18750 exact

typedef unsigned short ushort_t;
typedef short bf16x8 __attribute__((ext_vector_type(8)));
typedef short s2v    __attribute__((ext_vector_type(2)));
typedef float f32x4  __attribute__((ext_vector_type(4)));

__device__ __forceinline__ short f2bf(float f) {
    unsigned u = __builtin_bit_cast(unsigned, f);
    u = (u + 0x7fffu + ((u >> 16) & 1u)) >> 16;   // RNE
    return (short)u;
}
__device__ __forceinline__ float bf2f(ushort_t u) {
    return __builtin_bit_cast(float, (unsigned)u << 16);
}
__device__ __forceinline__ float bf2f_lo(unsigned p) {
    return __builtin_bit_cast(float, p << 16);
}
__device__ __forceinline__ float bf2f_hi(unsigned p) {
    return __builtin_bit_cast(float, p & 0xffff0000u);
}

// packed bf16x2 atomic add (HW global_atomic_pk_add_bf16 on gfx950)
__device__ __forceinline__ void pk_atomic_bf16(void* p, float m0, float m1) {
    s2v v; v[0] = f2bf(m0); v[1] = f2bf(m1);
#if __has_builtin(__builtin_amdgcn_global_atomic_fadd_v2bf16)
    typedef __attribute__((address_space(1))) s2v* gpt;
    __builtin_amdgcn_global_atomic_fadd_v2bf16((gpt)(unsigned long long)p, v);
#else
    unsigned* up = (unsigned*)p;
    unsigned old = __hip_atomic_load(up, __ATOMIC_RELAXED, __HIP_MEMORY_SCOPE_AGENT);
    unsigned assumed;
    do {
        assumed = old;
        float a0 = bf2f_lo(assumed) + m0;
        float a1 = bf2f_hi(assumed) + m1;
        unsigned nv = (unsigned)(ushort_t)f2bf(a0)
                    | ((unsigned)(ushort_t)f2bf(a1) << 16);
        old = atomicCAS(up, assumed, nv);
    } while (old != assumed);
#endif
}

// ---------------------------------------------------------------------------
// xcast: x fp32 -> bf16 (streaming) AND zero x1b (replaces the memset
// dispatch). Halves the edge kernel's random x-gather line demand; verified
// R4: FETCH 219.6 -> 148.9 MB. Numerically safe: message path is scaled by
// layer_scale=1e-6 in out; fp32 residual x is read by node_kernel.
// ---------------------------------------------------------------------------
__global__ __launch_bounds__(256) void xcast_kernel(
    const float* __restrict__ x, ushort_t* __restrict__ xb,
    ushort_t* __restrict__ x1b)
{
    const int stride = gridDim.x * 256;
    const uint2 z = make_uint2(0u, 0u);
    for (int k = blockIdx.x * 256 + threadIdx.x; k < N_NODES * C_CH / 4;
         k += stride) {
        const float4 v = *(const float4*)(x + 4 * (size_t)k);
        s2v a, b;
        a[0] = f2bf(v.x); a[1] = f2bf(v.y);
        b[0] = f2bf(v.z); b[1] = f2bf(v.w);
        uint2 o;
        o.x = __builtin_bit_cast(unsigned, a);
        o.y = __builtin_bit_cast(unsigned, b);
        *(uint2*)(xb + 4 * (size_t)k) = o;
        *(uint2*)(x1b + 4 * (size_t)k) = z;
    }
}

// ---------------------------------------------------------------------------
// K1 v5: barrier-free depthwise-conv message passing.
// R4 diagnosis: per-chunk __syncthreads forces vmcnt(0), draining the 8
// random-row pk-atomics every 16 edges -> latency-serialized (all pipes
// <30% busy, byte reductions don't move time). The 4 waves share NO data
// (sbuf[w] slices are wave-private), so the barriers only cost.
// R3's barrier-free NaN was a TBAA bug: short-typed LDS stores vs int-typed
// loads -> compiler licensed to drop the lgkmcnt ordering. Fix here:
// ALL LDS accesses are short-typed (may-alias -> waits inserted), plus
// asm memory fences at phase boundaries. HW side is safe: a wave's LDS ops
// complete in order.
// ---------------------------------------------------------------------------
__global__ __launch_bounds__(256) void edge_kernel(
    const ushort_t* __restrict__ xb, const float* __restrict__ kb,
    const int* __restrict__ ei, const float* __restrict__ kW,
    ushort_t* __restrict__ x1b)
{
    __shared__ short sbuf[4][16][68];   // 8.7 KB: [wave][edge-row][short col]

    const int t    = threadIdx.x;
    const int lane = t & 63;
    const int w    = __builtin_amdgcn_readfirstlane(t >> 6);
    const int nlo  = lane & 15;
    const int quad = lane >> 4;
    const int cp   = lane & 31;       // channel-pair index
    const int hf   = lane >> 5;       // half-wave: edge j vs j+8

    // B fragments: B[k][n] = kW[16t+n][k], lane k = quad*8+j
    bf16x8 bW[4];
    #pragma unroll
    for (int tt = 0; tt < 4; ++tt) {
        const float* p = kW + (size_t)(16 * tt + nlo) * KD + quad * 8;
        #pragma unroll
        for (int q = 0; q < 8; ++q) bW[tt][q] = f2bf(p[q]);
    }

    short* srow = &sbuf[w][0][0];     // row stride 68 shorts

    for (int c = blockIdx.x; c < NCHUNK; c += gridDim.x) {
        const int e0 = c * 64 + w * 16;

        // ---- MFMA coef for edges e0..e0+15 ----
        const float* ap = kb + (size_t)(e0 + nlo) * KD + quad * 8;
        bf16x8 af;
        #pragma unroll
        for (int q = 0; q < 8; ++q) af[q] = f2bf(ap[q]);
        #pragma unroll
        for (int tt = 0; tt < 4; ++tt) {
            f32x4 d = {0.f, 0.f, 0.f, 0.f};
            d = __builtin_amdgcn_mfma_f32_16x16x32_bf16(af, bW[tt], d, 0, 0, 0);
            #pragma unroll
            for (int r = 0; r < 4; ++r)
                srow[(quad * 4 + r) * 68 + 16 * tt + nlo] = f2bf(d[r]);
        }
        asm volatile("" ::: "memory");   // phase fence: order ds_write->ds_read

        // ---- scatter: 2 edges per instruction slot, full 64-lane use ----
        #pragma unroll
        for (int j = 0; j < 8; ++j) {
            const int sA = ei[e0 + j],           sB = ei[e0 + j + 8];
            const int dA = ei[E_EDGES + e0 + j], dB = ei[E_EDGES + e0 + j + 8];
            const int src = hf ? sB : sA;
            const int dst = hf ? dB : dA;
            const int ro  = (j + hf * 8) * 68 + 2 * cp;
            const unsigned lo = (ushort_t)srow[ro];
            const unsigned hi = (ushort_t)srow[ro + 1];
            const unsigned cf = lo | (hi << 16);
            const unsigned xv = *(const unsigned*)(xb + (size_t)src * C_CH + 2 * cp);
            pk_atomic_bf16(x1b + (size_t)dst * C_CH + 2 * cp,
                           bf2f_lo(xv) * bf2f_lo(cf),
                           bf2f_hi(xv) * bf2f_hi(cf));
        }
        asm volatile("" ::: "memory");   // phase fence: order reads->next writes
    }
}

// ---------------------------------------------------------------------------
// K2: conv_bias + LN (fp32) -> bf16 MFMA GEMM1 -> exact GELU -> bf16 MFMA
// GEMM2 -> layerscale + residual. x1 is bf16. (unchanged)
// ---------------------------------------------------------------------------
__global__ __launch_bounds__(256, 2) void node_kernel(
    const float* __restrict__ x,  const ushort_t* __restrict__ x1b,
    const float* __restrict__ conv_bias, const float* __restrict__ gamma,
    const float* __restrict__ beta, const float* __restrict__ W1,
    const float* __restrict__ b1, const float* __restrict__ W2,
    const float* __restrict__ b2, const float* __restrict__ ls,
    float* __restrict__ out)
{
    __shared__ short lnb[NPG][C_CH + 8];
    __shared__ short gb[NPG][HID + 8];

    const int t    = threadIdx.x;
    const int lane = t & 63;
    const int w    = t >> 6;
    const int nlo  = lane & 15;
    const int quad = lane >> 4;

    bf16x8 b1f[4][2];
    float  b1v[4];
    #pragma unroll
    for (int t1 = 0; t1 < 4; ++t1) {
        const int j = (4 * w + t1) * 16 + nlo;
        b1v[t1] = b1[j];
        #pragma unroll
        for (int s = 0; s < 2; ++s) {
            const float* p = W1 + (size_t)j * C_CH + s * 32 + quad * 8;
            #pragma unroll
            for (int q = 0; q < 8; ++q) b1f[t1][s][q] = f2bf(p[q]);
        }
    }
    bf16x8 b2f[8];
    #pragma unroll
    for (int s2 = 0; s2 < 8; ++s2) {
        const float* p = W2 + (size_t)(w * 16 + nlo) * HID + s2 * 32 + quad * 8;
        #pragma unroll
        for (int q = 0; q < 8; ++q) b2f[s2][q] = f2bf(p[q]);
    }
    const float biasc  = conv_bias[lane];
    const float gammac = gamma[lane];
    const float betac  = beta[lane];
    const float b2v    = b2[w * 16 + nlo];
    const float lsv    = ls[w * 16 + nlo];

    for (int g = blockIdx.x; g < NGROUPS; g += gridDim.x) {
        const int base = g * NPG;

        #pragma unroll
        for (int q = 0; q < 8; ++q) {
            const int loc = w * 8 + q;
            float v = bf2f(x1b[(size_t)(base + loc) * C_CH + lane]) + biasc;
            float s = v, ss = v * v;
            #pragma unroll
            for (int o = 32; o > 0; o >>= 1) {
                s  += __shfl_xor(s,  o, 64);
                ss += __shfl_xor(ss, o, 64);
            }
            float mu   = s * (1.f / 64.f);
            float rstd = rsqrtf(ss * (1.f / 64.f) - mu * mu + 1e-5f);
            lnb[loc][lane] = f2bf((v - mu) * rstd * gammac + betac);
        }
        __syncthreads();

        #pragma unroll
        for (int mt = 0; mt < 2; ++mt) {
            bf16x8 a1[2];
            #pragma unroll
            for (int s = 0; s < 2; ++s)
                a1[s] = *(const bf16x8*)&lnb[mt * 16 + nlo][s * 32 + quad * 8];
            #pragma unroll
            for (int t1 = 0; t1 < 4; ++t1) {
                f32x4 c = {0.f, 0.f, 0.f, 0.f};
                c = __builtin_amdgcn_mfma_f32_16x16x32_bf16(a1[0], b1f[t1][0], c, 0, 0, 0);
                c = __builtin_amdgcn_mfma_f32_16x16x32_bf16(a1[1], b1f[t1][1], c, 0, 0, 0);
                #pragma unroll
                for (int r = 0; r < 4; ++r) {
                    float h = c[r] + b1v[t1];
                    h = 0.5f * h * (1.f + erff(h * 0.70710678f));
                    gb[mt * 16 + quad * 4 + r][(4 * w + t1) * 16 + nlo] = f2bf(h);
                }
            }
        }
        __syncthreads();

        #pragma unroll
        for (int mt = 0; mt < 2; ++mt) {
            f32x4 c2 = {0.f, 0.f, 0.f, 0.f};
            #pragma unroll
            for (int s2 = 0; s2 < 8; ++s2) {
                bf16x8 a2 = *(const bf16x8*)&gb[mt * 16 + nlo][s2 * 32 + quad * 8];
                c2 = __builtin_amdgcn_mfma_f32_16x16x32_bf16(a2, b2f[s2], c2, 0, 0, 0);
            }
            #pragma unroll
            for (int r = 0; r < 4; ++r) {
                const int node = base + mt * 16 + quad * 4 + r;
                const int cch  = w * 16 + nlo;
                float h2 = c2[r] + b2v;
                out[(size_t)node * C_CH + cch] =
                    lsv * h2 + x[(size_t)node * C_CH + cch];
            }
        }
        __syncthreads();
    }
}

extern "C" void kernel_launch(void* const* d_in, const int* in_sizes, int n_in,
                              void* d_out, int out_size, void* d_ws, size_t ws_size,
                              hipStream_t stream) {
    const float* x   = (const float*)d_in[0];
    const float* kb  = (const float*)d_in[1];
    // d_in[2] = fiber_kernel_basis (unused)
    const int*   ei  = (const int*)d_in[3];
    const float* kW  = (const float*)d_in[4];
    const float* cb  = (const float*)d_in[5];
    const float* gm  = (const float*)d_in[6];
    const float* bt  = (const float*)d_in[7];
    const float* W1  = (const float*)d_in[8];
    const float* b1  = (const float*)d_in[9];
    const float* W2  = (const float*)d_in[10];
    const float* b2  = (const float*)d_in[11];
    const float* ls  = (const float*)d_in[12];
    float* out = (float*)d_out;

    // workspace: x1b bf16 accumulator (12.8 MB) + xb bf16 copy of x (12.8 MB)
    ushort_t* x1b = (ushort_t*)d_ws;
    ushort_t* xb  = (ushort_t*)d_ws + (size_t)N_NODES * C_CH;

    xcast_kernel<<<1024, 256, 0, stream>>>(x, xb, x1b);
    edge_kernel<<<4096, 256, 0, stream>>>(xb, kb, ei, kW, x1b);
    node_kernel<<<2048, 256, 0, stream>>>(x, x1b, cb, gm, bt, W1, b1, W2, b2, ls, out);
}